// Round 1
// baseline (1064.392 us; speedup 1.0000x reference)
//
#include <hip/hip_runtime.h>
#include <math.h>

#define Bn 8
#define Tn 1024
#define Dn 768
#define Hn 12
#define HDn 64
#define D3 (3 * Dn)

// ---------------------------------------------------------------------------
// Generic tiled fp32 GEMM with fused bias:  C[M,N] = A[M,K] @ W[K,N] + bias[N]
// 64x64 tile, BK=16, 256 threads, 4x4 micro-tile per thread.
// ---------------------------------------------------------------------------
__global__ __launch_bounds__(256)
void gemm_bias_kernel(const float* __restrict__ A, const float* __restrict__ W,
                      const float* __restrict__ bias, float* __restrict__ C,
                      int M, int N, int K)
{
    __shared__ float As[16][65];   // [k][m], +1 pad: bank = (k+m)%32
    __shared__ float Bs[16][64];   // [k][n], float4-aligned stores

    const int tid = threadIdx.x;
    const int tx  = tid & 15;      // 0..15 (col group)
    const int ty  = tid >> 4;      // 0..15 (row group)
    const int bm  = blockIdx.y * 64;
    const int bn  = blockIdx.x * 64;

    float acc[4][4] = {};

    for (int k0 = 0; k0 < K; k0 += 16) {
        // Load A tile (64 rows x 16 k), coalesced float4, store transposed
        {
            const int row = tid >> 2;            // 0..63
            const int c4  = (tid & 3) * 4;       // 0,4,8,12
            float4 v = *(const float4*)&A[(size_t)(bm + row) * K + k0 + c4];
            As[c4 + 0][row] = v.x;
            As[c4 + 1][row] = v.y;
            As[c4 + 2][row] = v.z;
            As[c4 + 3][row] = v.w;
        }
        // Load W tile (16 k x 64 n), coalesced float4
        {
            const int row = tid >> 4;            // 0..15
            const int c4  = (tid & 15) * 4;      // 0..60
            float4 v = *(const float4*)&W[(size_t)(k0 + row) * N + bn + c4];
            *(float4*)&Bs[row][c4] = v;
        }
        __syncthreads();

        #pragma unroll
        for (int k = 0; k < 16; ++k) {
            float a[4], b[4];
            #pragma unroll
            for (int i = 0; i < 4; ++i) a[i] = As[k][ty * 4 + i];
            #pragma unroll
            for (int j = 0; j < 4; ++j) b[j] = Bs[k][tx * 4 + j];
            #pragma unroll
            for (int i = 0; i < 4; ++i)
                #pragma unroll
                for (int j = 0; j < 4; ++j)
                    acc[i][j] += a[i] * b[j];
        }
        __syncthreads();
    }

    #pragma unroll
    for (int i = 0; i < 4; ++i) {
        const size_t r = (size_t)(bm + ty * 4 + i);
        #pragma unroll
        for (int j = 0; j < 4; ++j) {
            const int c = bn + tx * 4 + j;
            C[r * N + c] = acc[i][j] + bias[c];
        }
    }
}

// ---------------------------------------------------------------------------
// Flash-style causal attention.
// qkv layout: [B, T, 3, H, HD] flattened as [B*T, 3*D].
// One block per (q-tile of 64 rows, head, batch). 256 threads, 4x4 micro.
// Online softmax; P tile overlays the K tile buffer to fit LDS.
// attn_out layout: [B, T, D]  (t-major, ready for the proj GEMM)
// ---------------------------------------------------------------------------
__global__ __launch_bounds__(256)
void attn_kernel(const float* __restrict__ qkv, float* __restrict__ attn_out)
{
    __shared__ float Qs[64][65];
    __shared__ float KPs[64][65];   // K tile, later reused as P tile
    __shared__ float Vs[64][65];

    const int tid = threadIdx.x;
    const int tx  = tid & 15;
    const int ty  = tid >> 4;
    const int qt  = blockIdx.x;          // 0..15
    const int h   = blockIdx.y;          // 0..11
    const int b   = blockIdx.z;          // 0..7
    const int q0  = qt * 64;

    const size_t rowbase = (size_t)b * Tn;   // row index base into [B*T, 3D]

    // Load Q tile: 64 q-rows x 64 hd
    {
        const int row = tid >> 2;            // 0..63
        const int c0  = (tid & 3) * 16;      // 0,16,32,48
        const float* src = &qkv[(rowbase + q0 + row) * D3 + 0 * Dn + h * HDn + c0];
        #pragma unroll
        for (int i = 0; i < 4; ++i) {
            float4 v = *(const float4*)&src[i * 4];
            Qs[row][c0 + i * 4 + 0] = v.x;
            Qs[row][c0 + i * 4 + 1] = v.y;
            Qs[row][c0 + i * 4 + 2] = v.z;
            Qs[row][c0 + i * 4 + 3] = v.w;
        }
    }

    float m_run[4], l_run[4], o[4][4];
    #pragma unroll
    for (int i = 0; i < 4; ++i) {
        m_run[i] = -1e30f;
        l_run[i] = 0.0f;
        #pragma unroll
        for (int j = 0; j < 4; ++j) o[i][j] = 0.0f;
    }
    const float scale = 0.125f;   // 1/sqrt(64)

    for (int kt = 0; kt <= qt; ++kt) {
        const int k0 = kt * 64;
        __syncthreads();   // prev PV done (and Q visible on first iter)

        // Load K and V tiles
        {
            const int row = tid >> 2;
            const int c0  = (tid & 3) * 16;
            const float* ksrc = &qkv[(rowbase + k0 + row) * D3 + 1 * Dn + h * HDn + c0];
            const float* vsrc = &qkv[(rowbase + k0 + row) * D3 + 2 * Dn + h * HDn + c0];
            #pragma unroll
            for (int i = 0; i < 4; ++i) {
                float4 kv = *(const float4*)&ksrc[i * 4];
                KPs[row][c0 + i * 4 + 0] = kv.x;
                KPs[row][c0 + i * 4 + 1] = kv.y;
                KPs[row][c0 + i * 4 + 2] = kv.z;
                KPs[row][c0 + i * 4 + 3] = kv.w;
                float4 vv = *(const float4*)&vsrc[i * 4];
                Vs[row][c0 + i * 4 + 0] = vv.x;
                Vs[row][c0 + i * 4 + 1] = vv.y;
                Vs[row][c0 + i * 4 + 2] = vv.z;
                Vs[row][c0 + i * 4 + 3] = vv.w;
            }
        }
        __syncthreads();

        // Scores: S[4][4], rows ty*4+i, cols tx*4+j
        float s[4][4] = {};
        #pragma unroll 8
        for (int k = 0; k < 64; ++k) {
            float a[4], bb[4];
            #pragma unroll
            for (int i = 0; i < 4; ++i) a[i]  = Qs[ty * 4 + i][k];
            #pragma unroll
            for (int j = 0; j < 4; ++j) bb[j] = KPs[tx * 4 + j][k];
            #pragma unroll
            for (int i = 0; i < 4; ++i)
                #pragma unroll
                for (int j = 0; j < 4; ++j)
                    s[i][j] += a[i] * bb[j];
        }

        // Scale + causal mask (only diagonal tile needs masking)
        #pragma unroll
        for (int i = 0; i < 4; ++i)
            #pragma unroll
            for (int j = 0; j < 4; ++j) {
                s[i][j] *= scale;
                if (kt == qt) {
                    const int qg = q0 + ty * 4 + i;
                    const int kg = k0 + tx * 4 + j;
                    if (kg > qg) s[i][j] = -1e30f;
                }
            }

        // Online softmax per row (reduce across the 16 tx lanes)
        float p[4][4];
        float rescale[4];
        #pragma unroll
        for (int i = 0; i < 4; ++i) {
            float mt = s[i][0];
            #pragma unroll
            for (int j = 1; j < 4; ++j) mt = fmaxf(mt, s[i][j]);
            #pragma unroll
            for (int off = 1; off < 16; off <<= 1)
                mt = fmaxf(mt, __shfl_xor(mt, off, 64));
            const float m_new = fmaxf(m_run[i], mt);
            rescale[i] = __expf(m_run[i] - m_new);
            float lsum = 0.0f;
            #pragma unroll
            for (int j = 0; j < 4; ++j) {
                p[i][j] = __expf(s[i][j] - m_new);
                lsum += p[i][j];
            }
            #pragma unroll
            for (int off = 1; off < 16; off <<= 1)
                lsum += __shfl_xor(lsum, off, 64);
            l_run[i] = l_run[i] * rescale[i] + lsum;
            m_run[i] = m_new;
        }

        __syncthreads();   // everyone done reading KPs as K

        // Write P into the K buffer
        #pragma unroll
        for (int i = 0; i < 4; ++i)
            #pragma unroll
            for (int j = 0; j < 4; ++j)
                KPs[ty * 4 + i][tx * 4 + j] = p[i][j];
        __syncthreads();

        // PV: O[i][j] (+)= sum_k P[row][k] * V[k][d]
        #pragma unroll
        for (int i = 0; i < 4; ++i)
            #pragma unroll
            for (int j = 0; j < 4; ++j)
                o[i][j] *= rescale[i];
        #pragma unroll 8
        for (int k = 0; k < 64; ++k) {
            float pp[4], vv[4];
            #pragma unroll
            for (int i = 0; i < 4; ++i) pp[i] = KPs[ty * 4 + i][k];
            #pragma unroll
            for (int j = 0; j < 4; ++j) vv[j] = Vs[k][tx * 4 + j];
            #pragma unroll
            for (int i = 0; i < 4; ++i)
                #pragma unroll
                for (int j = 0; j < 4; ++j)
                    o[i][j] += pp[i] * vv[j];
        }
    }

    // Final: divide by l, write [B, T, D] with D index = h*64 + d
    #pragma unroll
    for (int i = 0; i < 4; ++i) {
        const float inv_l = 1.0f / l_run[i];
        const size_t row = (rowbase + q0 + ty * 4 + i);
        #pragma unroll
        for (int j = 0; j < 4; ++j) {
            attn_out[row * Dn + h * HDn + tx * 4 + j] = o[i][j] * inv_l;
        }
    }
}

extern "C" void kernel_launch(void* const* d_in, const int* in_sizes, int n_in,
                              void* d_out, int out_size, void* d_ws, size_t ws_size,
                              hipStream_t stream) {
    const float* x     = (const float*)d_in[0];   // [B,T,D]
    const float* Wqkv  = (const float*)d_in[1];   // [D,3D]
    const float* bqkv  = (const float*)d_in[2];   // [3D]
    const float* Wproj = (const float*)d_in[3];   // [D,D]
    const float* bproj = (const float*)d_in[4];   // [D]
    float* out = (float*)d_out;                   // [B,T,D]

    float* qkv  = (float*)d_ws;                           // [B*T, 3D]  72 MB
    float* attn = qkv + (size_t)Bn * Tn * D3;             // [B*T, D]   24 MB

    const int M = Bn * Tn;   // 8192

    // 1) QKV = x @ Wqkv + bqkv
    {
        dim3 grid(D3 / 64, M / 64);
        gemm_bias_kernel<<<grid, 256, 0, stream>>>(x, Wqkv, bqkv, qkv, M, D3, Dn);
    }
    // 2) causal MHA
    {
        dim3 grid(Tn / 64, Hn, Bn);
        attn_kernel<<<grid, 256, 0, stream>>>(qkv, attn);
    }
    // 3) out = attn @ Wproj + bproj
    {
        dim3 grid(Dn / 64, M / 64);
        gemm_bias_kernel<<<grid, 256, 0, stream>>>(attn, Wproj, bproj, out, M, Dn, Dn);
    }
}

// Round 2
// 201.759 us; speedup vs baseline: 5.2756x; 5.2756x over previous
//
#include <hip/hip_runtime.h>

#define Bn 8
#define Tn 1024
#define Dn 768
#define Hn 12
#define HDn 64
#define D3 (3 * Dn)

typedef float f32x4 __attribute__((ext_vector_type(4)));
typedef short bf16x8 __attribute__((ext_vector_type(8)));
typedef unsigned short u16;

__device__ __forceinline__ u16 f2b(float f) {
    unsigned u = __builtin_bit_cast(unsigned, f);
    u += 0x7fffu + ((u >> 16) & 1u);
    return (u16)(u >> 16);
}

__device__ __forceinline__ void async_lds16(void* lds, const void* g) {
    __builtin_amdgcn_global_load_lds(
        (const __attribute__((address_space(1))) unsigned int*)g,
        (__attribute__((address_space(3))) unsigned int*)lds, 16, 0, 0);
}

// ---------------------------------------------------------------------------
// fp32 -> bf16 elementwise convert (n divisible by 4)
// ---------------------------------------------------------------------------
__global__ __launch_bounds__(256)
void conv_bf16_kernel(const float* __restrict__ in, u16* __restrict__ out, int n)
{
    int i = (blockIdx.x * 256 + threadIdx.x) * 4;
    if (i >= n) return;
    float4 v = *(const float4*)&in[i];
    union { u16 u[4]; uint2 p; } r;
    r.u[0] = f2b(v.x); r.u[1] = f2b(v.y); r.u[2] = f2b(v.z); r.u[3] = f2b(v.w);
    *(uint2*)&out[i] = r.p;
}

// ---------------------------------------------------------------------------
// W[K][N] fp32 -> WT[N][K] bf16  (64x64 tiles)
// ---------------------------------------------------------------------------
__global__ __launch_bounds__(256)
void transpose_bf16_kernel(const float* __restrict__ W, u16* __restrict__ WT,
                           int K, int N)
{
    __shared__ float Ls[64][65];
    const int bk = blockIdx.y * 64, bn = blockIdx.x * 64;
    const int r  = threadIdx.x >> 2;
    const int c0 = (threadIdx.x & 3) * 16;
    #pragma unroll
    for (int i = 0; i < 4; ++i) {
        float4 v = *(const float4*)&W[(size_t)(bk + r) * N + bn + c0 + i * 4];
        Ls[r][c0 + i * 4 + 0] = v.x;
        Ls[r][c0 + i * 4 + 1] = v.y;
        Ls[r][c0 + i * 4 + 2] = v.z;
        Ls[r][c0 + i * 4 + 3] = v.w;
    }
    __syncthreads();
    // thread writes WT[bn+r][bk+c0 .. +15], coalesced along k
    #pragma unroll
    for (int i = 0; i < 16; ++i) {
        WT[(size_t)(bn + r) * K + bk + c0 + i] = f2b(Ls[c0 + i][r]);
    }
}

// ---------------------------------------------------------------------------
// bf16 MFMA GEMM:  C[M,N] = A[M,K](bf16) @ BT[N,K](bf16)^T + bias
// 128x128 tile, BK=64, 256 thr = 4 waves (2x2), each wave 64x64 = 4x4 frags.
// global_load_lds w=16, XOR-swizzled source (octet ^= row&7), linear LDS.
// ---------------------------------------------------------------------------
template <int OUT_BF16>
__global__ __launch_bounds__(256)
void gemm_mfma_kernel(const u16* __restrict__ A, const u16* __restrict__ BT,
                      const float* __restrict__ bias, void* __restrict__ Cout,
                      int M, int N, int K)
{
    __shared__ u16 As[128 * 64];
    __shared__ u16 Bs[128 * 64];
    const int tid  = threadIdx.x;
    const int w    = tid >> 6;
    const int lane = tid & 63;
    const int li   = lane & 15;
    const int g    = lane >> 4;
    const int wm   = w >> 1, wn = w & 1;
    const int bm   = blockIdx.y * 128;
    const int bn   = blockIdx.x * 128;

    f32x4 acc[4][4];
    #pragma unroll
    for (int i = 0; i < 4; ++i)
        #pragma unroll
        for (int j = 0; j < 4; ++j)
            acc[i][j] = (f32x4){0.f, 0.f, 0.f, 0.f};

    for (int k0 = 0; k0 < K; k0 += 64) {
        __syncthreads();   // prev-iter frag reads complete before overwrite
        #pragma unroll
        for (int inst = 0; inst < 4; ++inst) {
            const int L   = inst * 256 + tid;      // 16B-chunk id, 0..1023
            const int row = L >> 3;                // 0..127
            const int gp  = (L & 7) ^ (row & 7);   // swizzled source octet
            async_lds16(&As[(inst * 256 + w * 64) * 8],
                        &A[(size_t)(bm + row) * K + k0 + gp * 8]);
            async_lds16(&Bs[(inst * 256 + w * 64) * 8],
                        &BT[(size_t)(bn + row) * K + k0 + gp * 8]);
        }
        __syncthreads();

        #pragma unroll
        for (int kc = 0; kc < 2; ++kc) {
            bf16x8 af[4], bfr[4];
            #pragma unroll
            for (int fm = 0; fm < 4; ++fm) {
                const int off = (wm * 64 + fm * 16 + li) * 64 +
                                (((kc * 4 + g) * 8) ^ ((li & 7) * 8));
                af[fm] = *(const bf16x8*)&As[off];
            }
            #pragma unroll
            for (int fn = 0; fn < 4; ++fn) {
                const int off = (wn * 64 + fn * 16 + li) * 64 +
                                (((kc * 4 + g) * 8) ^ ((li & 7) * 8));
                bfr[fn] = *(const bf16x8*)&Bs[off];
            }
            #pragma unroll
            for (int fm = 0; fm < 4; ++fm)
                #pragma unroll
                for (int fn = 0; fn < 4; ++fn)
                    acc[fm][fn] = __builtin_amdgcn_mfma_f32_16x16x32_bf16(
                        af[fm], bfr[fn], acc[fm][fn], 0, 0, 0);
        }
    }

    #pragma unroll
    for (int fm = 0; fm < 4; ++fm) {
        #pragma unroll
        for (int reg = 0; reg < 4; ++reg) {
            const size_t row = (size_t)(bm + wm * 64 + fm * 16 + g * 4 + reg);
            #pragma unroll
            for (int fn = 0; fn < 4; ++fn) {
                const int col = bn + wn * 64 + fn * 16 + li;
                const float v = acc[fm][fn][reg] + bias[col];
                if (OUT_BF16) ((u16*)Cout)[row * N + col] = f2b(v);
                else          ((float*)Cout)[row * N + col] = v;
            }
        }
    }
}

// ---------------------------------------------------------------------------
// MFMA flash attention (causal).  qkvb: [B*T, 3D] bf16.  attnb: [B*T, D] bf16.
// Block = 256 thr (4 waves); Q tile = 64 rows (16/wave); KV tile = 64.
// K staged via swizzled global_load_lds; V reg-staged transposed into LDS;
// P round-trips through a per-wave LDS slice. fp32 online softmax.
// ---------------------------------------------------------------------------
__global__ __launch_bounds__(256)
void attn_mfma_kernel(const u16* __restrict__ qkvb, u16* __restrict__ attnb)
{
    __shared__ u16 Ks[64 * 64];   // [key][hd], octet ^= key&7
    __shared__ u16 VT[64 * 64];   // [hd][key], key-elem ^= (hd&7)<<3
    __shared__ u16 Pb[64 * 64];   // [qrow][key], key-elem ^= (row&7)<<3

    const int tid  = threadIdx.x;
    const int w    = tid >> 6;
    const int lane = tid & 63;
    const int li   = lane & 15;
    const int g    = lane >> 4;
    const int qt   = blockIdx.x;          // 0..15
    const int h    = blockIdx.y;          // 0..11
    const int b    = blockIdx.z;          // 0..7
    const int q0   = qt * 64;
    const size_t rowbase = (size_t)b * Tn;

    // Q fragments (A operand), held in registers for the whole block
    bf16x8 qf[2];
    #pragma unroll
    for (int kc = 0; kc < 2; ++kc)
        qf[kc] = *(const bf16x8*)&qkvb[(rowbase + q0 + w * 16 + li) * D3 +
                                       h * HDn + (kc * 4 + g) * 8];

    f32x4 of[4];
    #pragma unroll
    for (int fn = 0; fn < 4; ++fn) of[fn] = (f32x4){0.f, 0.f, 0.f, 0.f};
    float m_run[4], l_run[4];
    #pragma unroll
    for (int r = 0; r < 4; ++r) { m_run[r] = -1e30f; l_run[r] = 0.f; }

    for (int kt = 0; kt <= qt; ++kt) {
        const int k0 = kt * 64;
        __syncthreads();   // prev-iter Ks/VT reads done before restage

        // stage K: 8KB via global_load_lds, swizzled source
        #pragma unroll
        for (int inst = 0; inst < 2; ++inst) {
            const int L   = inst * 256 + tid;    // 0..511
            const int row = L >> 3;              // key 0..63
            const int gp  = (L & 7) ^ (row & 7);
            async_lds16(&Ks[(inst * 256 + w * 64) * 8],
                        &qkvb[(rowbase + k0 + row) * D3 + Dn + h * HDn + gp * 8]);
        }
        // stage V transposed: reg load + swizzled scattered b16 writes
        {
            const int key = tid >> 2;
            const int hd0 = (tid & 3) * 16;
            const size_t base = (rowbase + k0 + key) * D3 + 2 * Dn + h * HDn;
            bf16x8 v0 = *(const bf16x8*)&qkvb[base + hd0];
            bf16x8 v1 = *(const bf16x8*)&qkvb[base + hd0 + 8];
            #pragma unroll
            for (int i = 0; i < 8; ++i) {
                const int hdA = hd0 + i, hdB = hd0 + 8 + i;
                VT[hdA * 64 + (key ^ ((hdA & 7) << 3))] = (u16)v0[i];
                VT[hdB * 64 + (key ^ ((hdB & 7) << 3))] = (u16)v1[i];
            }
        }
        __syncthreads();

        // S = Q K^T  (per wave: 16 q-rows x 64 keys)
        f32x4 s[4];
        #pragma unroll
        for (int nf = 0; nf < 4; ++nf) s[nf] = (f32x4){0.f, 0.f, 0.f, 0.f};
        #pragma unroll
        for (int kc = 0; kc < 2; ++kc) {
            #pragma unroll
            for (int nf = 0; nf < 4; ++nf) {
                const int off = (nf * 16 + li) * 64 +
                                (((kc * 4 + g) * 8) ^ ((li & 7) * 8));
                bf16x8 kf = *(const bf16x8*)&Ks[off];
                s[nf] = __builtin_amdgcn_mfma_f32_16x16x32_bf16(qf[kc], kf, s[nf], 0, 0, 0);
            }
        }

        // scale + causal mask; lane holds rows g*4+reg, col nf*16+li
        float ss[4][4];
        #pragma unroll
        for (int nf = 0; nf < 4; ++nf)
            #pragma unroll
            for (int reg = 0; reg < 4; ++reg) {
                float sv = s[nf][reg] * 0.125f;
                if (kt == qt) {
                    const int kg = k0 + nf * 16 + li;
                    const int qg = q0 + w * 16 + g * 4 + reg;
                    if (kg > qg) sv = -1e30f;
                }
                ss[nf][reg] = sv;
            }

        // online softmax (reduce across 16 lanes of the col dim)
        float resc[4], p[4][4];
        #pragma unroll
        for (int reg = 0; reg < 4; ++reg) {
            float mt = ss[0][reg];
            #pragma unroll
            for (int nf = 1; nf < 4; ++nf) mt = fmaxf(mt, ss[nf][reg]);
            #pragma unroll
            for (int off = 1; off < 16; off <<= 1)
                mt = fmaxf(mt, __shfl_xor(mt, off, 64));
            const float mnew = fmaxf(m_run[reg], mt);
            resc[reg] = __expf(m_run[reg] - mnew);
            float ls = 0.f;
            #pragma unroll
            for (int nf = 0; nf < 4; ++nf) {
                p[nf][reg] = __expf(ss[nf][reg] - mnew);
                ls += p[nf][reg];
            }
            #pragma unroll
            for (int off = 1; off < 16; off <<= 1)
                ls += __shfl_xor(ls, off, 64);
            l_run[reg] = l_run[reg] * resc[reg] + ls;
            m_run[reg] = mnew;
        }

        // write P (bf16) into per-wave LDS slice, swizzled
        #pragma unroll
        for (int nf = 0; nf < 4; ++nf)
            #pragma unroll
            for (int reg = 0; reg < 4; ++reg) {
                const int r = w * 16 + g * 4 + reg;
                Pb[r * 64 + ((nf * 16 + li) ^ ((r & 7) << 3))] =
                    f2b(p[nf][reg]);
            }

        // rescale O
        #pragma unroll
        for (int fn = 0; fn < 4; ++fn)
            #pragma unroll
            for (int reg = 0; reg < 4; ++reg)
                of[fn][reg] *= resc[reg];

        // O += P V
        #pragma unroll
        for (int kc = 0; kc < 2; ++kc) {
            const int poff = (w * 16 + li) * 64 +
                             (((kc * 4 + g) * 8) ^ ((li & 7) * 8));
            bf16x8 pf = *(const bf16x8*)&Pb[poff];
            #pragma unroll
            for (int fn = 0; fn < 4; ++fn) {
                const int voff = (fn * 16 + li) * 64 +
                                 (((kc * 4 + g) * 8) ^ ((li & 7) * 8));
                bf16x8 vf = *(const bf16x8*)&VT[voff];
                of[fn] = __builtin_amdgcn_mfma_f32_16x16x32_bf16(pf, vf, of[fn], 0, 0, 0);
            }
        }
    }

    // epilogue: normalize and store bf16 [B*T, D]
    #pragma unroll
    for (int reg = 0; reg < 4; ++reg) {
        const float inv = 1.f / l_run[reg];
        const size_t row = rowbase + q0 + w * 16 + g * 4 + reg;
        #pragma unroll
        for (int fn = 0; fn < 4; ++fn) {
            attnb[row * Dn + h * HDn + fn * 16 + li] = f2b(of[fn][reg] * inv);
        }
    }
}

extern "C" void kernel_launch(void* const* d_in, const int* in_sizes, int n_in,
                              void* d_out, int out_size, void* d_ws, size_t ws_size,
                              hipStream_t stream) {
    const float* x     = (const float*)d_in[0];   // [B,T,D]
    const float* Wqkv  = (const float*)d_in[1];   // [D,3D]
    const float* bqkv  = (const float*)d_in[2];   // [3D]
    const float* Wproj = (const float*)d_in[3];   // [D,D]
    const float* bproj = (const float*)d_in[4];   // [D]
    float* out = (float*)d_out;                   // [B,T,D] fp32

    const int M = Bn * Tn;                        // 8192

    char* ws = (char*)d_ws;
    u16* qkvb   = (u16*)ws;                                   ws += (size_t)M * D3 * 2;  // 37.75 MB
    u16* xb     = (u16*)ws;                                   ws += (size_t)M * Dn * 2;  // 12.6 MB
    u16* attnb  = (u16*)ws;                                   ws += (size_t)M * Dn * 2;  // 12.6 MB
    u16* WqkvT  = (u16*)ws;                                   ws += (size_t)D3 * Dn * 2; // 3.5 MB
    u16* WprojT = (u16*)ws;                                   // 1.2 MB

    // x -> bf16
    conv_bf16_kernel<<<(M * Dn / 4 + 255) / 256, 256, 0, stream>>>(x, xb, M * Dn);
    // W -> W^T bf16
    {
        dim3 gq(D3 / 64, Dn / 64);
        transpose_bf16_kernel<<<gq, 256, 0, stream>>>(Wqkv, WqkvT, Dn, D3);
        dim3 gp(Dn / 64, Dn / 64);
        transpose_bf16_kernel<<<gp, 256, 0, stream>>>(Wproj, WprojT, Dn, Dn);
    }
    // qkv = x @ Wqkv + bqkv   (bf16 out)
    {
        dim3 grid(D3 / 128, M / 128);
        gemm_mfma_kernel<1><<<grid, 256, 0, stream>>>(xb, WqkvT, bqkv, qkvb, M, D3, Dn);
    }
    // causal MHA (bf16 out)
    {
        dim3 grid(Tn / 64, Hn, Bn);
        attn_mfma_kernel<<<grid, 256, 0, stream>>>(qkvb, attnb);
    }
    // out = attn @ Wproj + bproj  (fp32 out)
    {
        dim3 grid(Dn / 128, M / 128);
        gemm_mfma_kernel<0><<<grid, 256, 0, stream>>>(attnb, WprojT, bproj, out, M, Dn, Dn);
    }
}

// Round 3
// 154.309 us; speedup vs baseline: 6.8978x; 1.3075x over previous
//
#include <hip/hip_runtime.h>

#define Bn 8
#define Tn 1024
#define Dn 768
#define Hn 12
#define HDn 64
#define D3 (3 * Dn)

typedef float f32x4 __attribute__((ext_vector_type(4)));
typedef short bf16x8 __attribute__((ext_vector_type(8)));
typedef unsigned short u16;

// softmax computed in exp2 domain: scale = (1/sqrt(64)) * log2(e)
#define SM_SCALE 0.18033688011112042f

__device__ __forceinline__ u16 f2b(float f) {
    unsigned u = __builtin_bit_cast(unsigned, f);
    u += 0x7fffu + ((u >> 16) & 1u);
    return (u16)(u >> 16);
}

__device__ __forceinline__ void async_lds16(void* lds, const void* g) {
    __builtin_amdgcn_global_load_lds(
        (const __attribute__((address_space(1))) unsigned int*)g,
        (__attribute__((address_space(3))) unsigned int*)lds, 16, 0, 0);
}

// ---------------------------------------------------------------------------
// fp32 -> bf16 elementwise convert (n divisible by 4)
// ---------------------------------------------------------------------------
__global__ __launch_bounds__(256)
void conv_bf16_kernel(const float* __restrict__ in, u16* __restrict__ out, int n)
{
    int i = (blockIdx.x * 256 + threadIdx.x) * 4;
    if (i >= n) return;
    float4 v = *(const float4*)&in[i];
    union { u16 u[4]; uint2 p; } r;
    r.u[0] = f2b(v.x); r.u[1] = f2b(v.y); r.u[2] = f2b(v.z); r.u[3] = f2b(v.w);
    *(uint2*)&out[i] = r.p;
}

// ---------------------------------------------------------------------------
// W[K][N] fp32 -> WT[N][K] bf16  (64x64 tiles)
// ---------------------------------------------------------------------------
__global__ __launch_bounds__(256)
void transpose_bf16_kernel(const float* __restrict__ W, u16* __restrict__ WT,
                           int K, int N)
{
    __shared__ float Ls[64][65];
    const int bk = blockIdx.y * 64, bn = blockIdx.x * 64;
    const int r  = threadIdx.x >> 2;
    const int c0 = (threadIdx.x & 3) * 16;
    #pragma unroll
    for (int i = 0; i < 4; ++i) {
        float4 v = *(const float4*)&W[(size_t)(bk + r) * N + bn + c0 + i * 4];
        Ls[r][c0 + i * 4 + 0] = v.x;
        Ls[r][c0 + i * 4 + 1] = v.y;
        Ls[r][c0 + i * 4 + 2] = v.z;
        Ls[r][c0 + i * 4 + 3] = v.w;
    }
    __syncthreads();
    #pragma unroll
    for (int i = 0; i < 16; ++i) {
        WT[(size_t)(bn + r) * K + bk + c0 + i] = f2b(Ls[c0 + i][r]);
    }
}

// ---------------------------------------------------------------------------
// bf16 MFMA GEMM:  C[M,N] = A[M,K](bf16) @ BT[N,K](bf16)^T + bias
// 128x128 tile, BK=64, 256 thr = 4 waves (2x2), each wave 64x64 = 4x4 frags.
// MODE 0: fp32 C.  MODE 1 (QKV): cols<1536 -> bf16 qkv; cols>=1536 -> V
// transposed into VT[b,h,d,t] (packed 4-row 8B stores).
// ---------------------------------------------------------------------------
template <int MODE>
__global__ __launch_bounds__(256)
void gemm_mfma_kernel(const u16* __restrict__ A, const u16* __restrict__ BT,
                      const float* __restrict__ bias, void* __restrict__ Cout,
                      u16* __restrict__ VTout, int M, int N, int K)
{
    __shared__ u16 As[128 * 64];
    __shared__ u16 Bs[128 * 64];
    const int tid  = threadIdx.x;
    const int w    = tid >> 6;
    const int lane = tid & 63;
    const int li   = lane & 15;
    const int g    = lane >> 4;
    const int wm   = w >> 1, wn = w & 1;
    const int bm   = blockIdx.y * 128;
    const int bn   = blockIdx.x * 128;

    f32x4 acc[4][4];
    #pragma unroll
    for (int i = 0; i < 4; ++i)
        #pragma unroll
        for (int j = 0; j < 4; ++j)
            acc[i][j] = (f32x4){0.f, 0.f, 0.f, 0.f};

    for (int k0 = 0; k0 < K; k0 += 64) {
        __syncthreads();
        #pragma unroll
        for (int inst = 0; inst < 4; ++inst) {
            const int L   = inst * 256 + tid;
            const int row = L >> 3;
            const int gp  = (L & 7) ^ (row & 7);
            async_lds16(&As[(inst * 256 + w * 64) * 8],
                        &A[(size_t)(bm + row) * K + k0 + gp * 8]);
            async_lds16(&Bs[(inst * 256 + w * 64) * 8],
                        &BT[(size_t)(bn + row) * K + k0 + gp * 8]);
        }
        __syncthreads();

        #pragma unroll
        for (int kc = 0; kc < 2; ++kc) {
            bf16x8 af[4], bfr[4];
            #pragma unroll
            for (int fm = 0; fm < 4; ++fm) {
                const int off = (wm * 64 + fm * 16 + li) * 64 +
                                (((kc * 4 + g) * 8) ^ ((li & 7) * 8));
                af[fm] = *(const bf16x8*)&As[off];
            }
            #pragma unroll
            for (int fn = 0; fn < 4; ++fn) {
                const int off = (wn * 64 + fn * 16 + li) * 64 +
                                (((kc * 4 + g) * 8) ^ ((li & 7) * 8));
                bfr[fn] = *(const bf16x8*)&Bs[off];
            }
            #pragma unroll
            for (int fm = 0; fm < 4; ++fm)
                #pragma unroll
                for (int fn = 0; fn < 4; ++fn)
                    acc[fm][fn] = __builtin_amdgcn_mfma_f32_16x16x32_bf16(
                        af[fm], bfr[fn], acc[fm][fn], 0, 0, 0);
        }
    }

    if (MODE == 1 && bn >= 2 * Dn) {
        // V tile -> VT[b,h,d,t], 4 consecutive t rows packed per 8B store
        #pragma unroll
        for (int fm = 0; fm < 4; ++fm) {
            const int t0g = bm + wm * 64 + fm * 16 + g * 4;
            const int bb = t0g >> 10, tt = t0g & 1023;
            #pragma unroll
            for (int fn = 0; fn < 4; ++fn) {
                const int ncol = bn + wn * 64 + fn * 16 + li;
                const float bs = bias[ncol];
                const int cv = ncol - 2 * Dn;
                const int hv = cv >> 6, dv = cv & 63;
                union { u16 u[4]; uint2 p; } r;
                #pragma unroll
                for (int reg = 0; reg < 4; ++reg)
                    r.u[reg] = f2b(acc[fm][fn][reg] + bs);
                *(uint2*)&VTout[(((size_t)bb * Hn + hv) * HDn + dv) * Tn + tt] = r.p;
            }
        }
    } else {
        #pragma unroll
        for (int fm = 0; fm < 4; ++fm) {
            #pragma unroll
            for (int reg = 0; reg < 4; ++reg) {
                const size_t row = (size_t)(bm + wm * 64 + fm * 16 + g * 4 + reg);
                #pragma unroll
                for (int fn = 0; fn < 4; ++fn) {
                    const int col = bn + wn * 64 + fn * 16 + li;
                    const float v = acc[fm][fn][reg] + bias[col];
                    if (MODE == 1) ((u16*)Cout)[row * N + col] = f2b(v);
                    else           ((float*)Cout)[row * N + col] = v;
                }
            }
        }
    }
}

// ---------------------------------------------------------------------------
// Barrier-free MFMA flash attention (causal).
// Block = 256 thr (4 waves); each wave owns 32 q-rows; block covers 128.
// K read directly from qkvb (L2-resident, d-contiguous); V from VT[b,h,d,t]
// (key-contiguous). P round-trips through a per-wave LDS slice (no syncs).
// Waves exit the KV loop at their own causal bound; blocks launched
// long-first with XCD co-location of same-(b,h) blocks.
// ---------------------------------------------------------------------------
__global__ __launch_bounds__(256)
void attn_mfma_kernel(const u16* __restrict__ qkvb, const u16* __restrict__ VT,
                      u16* __restrict__ attnb)
{
    __shared__ u16 Pb[4][32 * 64];   // per-wave P slice, col ^= (row&7)<<3

    const int tid  = threadIdx.x;
    const int w    = tid >> 6;
    const int lane = tid & 63;
    const int li   = lane & 15;
    const int g    = lane >> 4;

    // flat-id decode: same-(b,h) blocks share an XCD (fid%8 heuristic),
    // longest q-tiles dispatched first.
    const int fid = blockIdx.x;            // 0..767
    const int xcd = fid & 7, j = fid >> 3; // j 0..95
    const int bh  = xcd + 8 * (j % 12);    // 0..95
    const int qt  = 7 - (j / 12);          // 7..0
    const int b   = bh / 12, h = bh % 12;

    const int q0   = qt * 128;
    const int wrow = q0 + w * 32;          // wave's first q-row
    const size_t rowbase = (size_t)b * Tn;
    const u16* vbase = VT + (size_t)bh * HDn * Tn;

    // Q fragments (A operand), resident all kernel
    bf16x8 qf[2][2];
    #pragma unroll
    for (int rh = 0; rh < 2; ++rh)
        #pragma unroll
        for (int kc = 0; kc < 2; ++kc)
            qf[rh][kc] = *(const bf16x8*)&qkvb[
                (rowbase + wrow + rh * 16 + li) * D3 + h * HDn + kc * 32 + g * 8];

    f32x4 of[2][4];
    float m_run[2][4], l_run[2][4];
    #pragma unroll
    for (int rh = 0; rh < 2; ++rh) {
        #pragma unroll
        for (int nf = 0; nf < 4; ++nf) of[rh][nf] = (f32x4){0.f, 0.f, 0.f, 0.f};
        #pragma unroll
        for (int r = 0; r < 4; ++r) { m_run[rh][r] = -1e30f; l_run[rh][r] = 0.f; }
    }

    const int nkt = (wrow >> 6) + 1;   // per-wave causal bound
    for (int kt = 0; kt < nkt; ++kt) {
        const int k0 = kt * 64;
        const bool maskit = (kt == nkt - 1);
        const u16* kbase = &qkvb[(rowbase + k0) * D3 + Dn + h * HDn];

        // S = Q K^T : K B-frags straight from global (L1/L2-hit)
        f32x4 s[2][4];
        #pragma unroll
        for (int rh = 0; rh < 2; ++rh)
            #pragma unroll
            for (int nf = 0; nf < 4; ++nf) s[rh][nf] = (f32x4){0.f, 0.f, 0.f, 0.f};
        #pragma unroll
        for (int kc = 0; kc < 2; ++kc) {
            #pragma unroll
            for (int nf = 0; nf < 4; ++nf) {
                const bf16x8 kf = *(const bf16x8*)&kbase[
                    (size_t)(nf * 16 + li) * D3 + kc * 32 + g * 8];
                s[0][nf] = __builtin_amdgcn_mfma_f32_16x16x32_bf16(qf[0][kc], kf, s[0][nf], 0, 0, 0);
                s[1][nf] = __builtin_amdgcn_mfma_f32_16x16x32_bf16(qf[1][kc], kf, s[1][nf], 0, 0, 0);
            }
        }

        // softmax per row-half (exp2 domain)
        #pragma unroll
        for (int rh = 0; rh < 2; ++rh) {
            float ss[4][4];
            #pragma unroll
            for (int nf = 0; nf < 4; ++nf)
                #pragma unroll
                for (int reg = 0; reg < 4; ++reg) {
                    float sv = s[rh][nf][reg] * SM_SCALE;
                    if (maskit) {
                        const int kg = k0 + nf * 16 + li;
                        const int qg = wrow + rh * 16 + g * 4 + reg;
                        if (kg > qg) sv = -1e30f;
                    }
                    ss[nf][reg] = sv;
                }
            float resc[4];
            #pragma unroll
            for (int reg = 0; reg < 4; ++reg) {
                float mt = fmaxf(fmaxf(ss[0][reg], ss[1][reg]),
                                 fmaxf(ss[2][reg], ss[3][reg]));
                #pragma unroll
                for (int off = 1; off < 16; off <<= 1)
                    mt = fmaxf(mt, __shfl_xor(mt, off, 64));
                const float mnew = fmaxf(m_run[rh][reg], mt);
                resc[reg] = exp2f(m_run[rh][reg] - mnew);
                float pr[4];
                float ls = 0.f;
                #pragma unroll
                for (int nf = 0; nf < 4; ++nf) {
                    pr[nf] = exp2f(ss[nf][reg] - mnew);
                    ls += pr[nf];
                }
                #pragma unroll
                for (int off = 1; off < 16; off <<= 1)
                    ls += __shfl_xor(ls, off, 64);
                l_run[rh][reg] = l_run[rh][reg] * resc[reg] + ls;
                m_run[rh][reg] = mnew;
                const int r = rh * 16 + g * 4 + reg;
                #pragma unroll
                for (int nf = 0; nf < 4; ++nf)
                    Pb[w][r * 64 + ((nf * 16 + li) ^ ((r & 7) << 3))] = f2b(pr[nf]);
            }
            #pragma unroll
            for (int nf = 0; nf < 4; ++nf)
                #pragma unroll
                for (int reg = 0; reg < 4; ++reg)
                    of[rh][nf][reg] *= resc[reg];
        }

        // O += P V : V B-frags from VT (key-contiguous), P from wave LDS slice
        #pragma unroll
        for (int kc = 0; kc < 2; ++kc) {
            const int pco = kc * 32 + g * 8;
            const bf16x8 pf0 = *(const bf16x8*)&Pb[w][(li) * 64 + (pco ^ ((li & 7) << 3))];
            const bf16x8 pf1 = *(const bf16x8*)&Pb[w][(16 + li) * 64 + (pco ^ ((li & 7) << 3))];
            #pragma unroll
            for (int nf = 0; nf < 4; ++nf) {
                const bf16x8 vf = *(const bf16x8*)&vbase[
                    (size_t)(nf * 16 + li) * Tn + k0 + kc * 32 + g * 8];
                of[0][nf] = __builtin_amdgcn_mfma_f32_16x16x32_bf16(pf0, vf, of[0][nf], 0, 0, 0);
                of[1][nf] = __builtin_amdgcn_mfma_f32_16x16x32_bf16(pf1, vf, of[1][nf], 0, 0, 0);
            }
        }
    }

    // epilogue: normalize, store bf16 [B*T, D]
    #pragma unroll
    for (int rh = 0; rh < 2; ++rh)
        #pragma unroll
        for (int reg = 0; reg < 4; ++reg) {
            const float inv = 1.f / l_run[rh][reg];
            const size_t row = rowbase + wrow + rh * 16 + g * 4 + reg;
            #pragma unroll
            for (int nf = 0; nf < 4; ++nf)
                attnb[row * Dn + h * HDn + nf * 16 + li] = f2b(of[rh][nf][reg] * inv);
        }
}

extern "C" void kernel_launch(void* const* d_in, const int* in_sizes, int n_in,
                              void* d_out, int out_size, void* d_ws, size_t ws_size,
                              hipStream_t stream) {
    const float* x     = (const float*)d_in[0];
    const float* Wqkv  = (const float*)d_in[1];
    const float* bqkv  = (const float*)d_in[2];
    const float* Wproj = (const float*)d_in[3];
    const float* bproj = (const float*)d_in[4];
    float* out = (float*)d_out;

    const int M = Bn * Tn;   // 8192

    char* ws = (char*)d_ws;
    u16* qkvb   = (u16*)ws;  ws += (size_t)M * D3 * 2;        // 37.75 MB
    u16* xb     = (u16*)ws;  ws += (size_t)M * Dn * 2;        // 12.6 MB
    u16* attnb  = (u16*)ws;  ws += (size_t)M * Dn * 2;        // 12.6 MB
    u16* VT     = (u16*)ws;  ws += (size_t)Bn * Hn * HDn * Tn * 2; // 12.6 MB
    u16* WqkvT  = (u16*)ws;  ws += (size_t)D3 * Dn * 2;       // 3.5 MB
    u16* WprojT = (u16*)ws;                                   // 1.2 MB

    conv_bf16_kernel<<<(M * Dn / 4 + 255) / 256, 256, 0, stream>>>(x, xb, M * Dn);
    {
        dim3 gq(D3 / 64, Dn / 64);
        transpose_bf16_kernel<<<gq, 256, 0, stream>>>(Wqkv, WqkvT, Dn, D3);
        dim3 gp(Dn / 64, Dn / 64);
        transpose_bf16_kernel<<<gp, 256, 0, stream>>>(Wproj, WprojT, Dn, Dn);
    }
    {
        dim3 grid(D3 / 128, M / 128);
        gemm_mfma_kernel<1><<<grid, 256, 0, stream>>>(xb, WqkvT, bqkv, qkvb, VT, M, D3, Dn);
    }
    attn_mfma_kernel<<<768, 256, 0, stream>>>(qkvb, VT, attnb);
    {
        dim3 grid(Dn / 128, M / 128);
        gemm_mfma_kernel<0><<<grid, 256, 0, stream>>>(attnb, WprojT, bproj, out, nullptr, M, Dn, Dn);
    }
}

// Round 4
// 148.007 us; speedup vs baseline: 7.1915x; 1.0426x over previous
//
#include <hip/hip_runtime.h>

#define Bn 8
#define Tn 1024
#define Dn 768
#define Hn 12
#define HDn 64
#define D3 (3 * Dn)

typedef float f32x4 __attribute__((ext_vector_type(4)));
typedef short bf16x8 __attribute__((ext_vector_type(8)));
typedef unsigned short u16;

// softmax computed in exp2 domain: scale = (1/sqrt(64)) * log2(e)
#define SM_SCALE 0.18033688011112042f

__device__ __forceinline__ u16 f2b(float f) {
    unsigned u = __builtin_bit_cast(unsigned, f);
    u += 0x7fffu + ((u >> 16) & 1u);
    return (u16)(u >> 16);
}

__device__ __forceinline__ void async_lds16(void* lds, const void* g) {
    __builtin_amdgcn_global_load_lds(
        (const __attribute__((address_space(1))) unsigned int*)g,
        (__attribute__((address_space(3))) unsigned int*)lds, 16, 0, 0);
}

// ---------------------------------------------------------------------------
// fp32 -> bf16 elementwise convert (n divisible by 4)
// ---------------------------------------------------------------------------
__global__ __launch_bounds__(256)
void conv_bf16_kernel(const float* __restrict__ in, u16* __restrict__ out, int n)
{
    int i = (blockIdx.x * 256 + threadIdx.x) * 4;
    if (i >= n) return;
    float4 v = *(const float4*)&in[i];
    union { u16 u[4]; uint2 p; } r;
    r.u[0] = f2b(v.x); r.u[1] = f2b(v.y); r.u[2] = f2b(v.z); r.u[3] = f2b(v.w);
    *(uint2*)&out[i] = r.p;
}

// ---------------------------------------------------------------------------
// W[K][N] fp32 -> WT[N][K] bf16  (64x64 tiles)
// ---------------------------------------------------------------------------
__global__ __launch_bounds__(256)
void transpose_bf16_kernel(const float* __restrict__ W, u16* __restrict__ WT,
                           int K, int N)
{
    __shared__ float Ls[64][65];
    const int bk = blockIdx.y * 64, bn = blockIdx.x * 64;
    const int r  = threadIdx.x >> 2;
    const int c0 = (threadIdx.x & 3) * 16;
    #pragma unroll
    for (int i = 0; i < 4; ++i) {
        float4 v = *(const float4*)&W[(size_t)(bk + r) * N + bn + c0 + i * 4];
        Ls[r][c0 + i * 4 + 0] = v.x;
        Ls[r][c0 + i * 4 + 1] = v.y;
        Ls[r][c0 + i * 4 + 2] = v.z;
        Ls[r][c0 + i * 4 + 3] = v.w;
    }
    __syncthreads();
    #pragma unroll
    for (int i = 0; i < 16; ++i) {
        WT[(size_t)(bn + r) * K + bk + c0 + i] = f2b(Ls[c0 + i][r]);
    }
}

// ---------------------------------------------------------------------------
// bf16 MFMA GEMM:  C[M,N] = A[M,K](bf16) @ BT[N,K](bf16)^T + bias
// 128x128 tile, BK=64, 256 thr = 4 waves (2x2), each wave 64x64 = 4x4 frags.
// MODE 0: fp32 C.  MODE 1 (QKV): cols<1536 -> bf16 qkv; cols>=1536 -> V
// transposed into VT[b,h,d,t] (packed 4-row 8B stores).
// ---------------------------------------------------------------------------
template <int MODE>
__global__ __launch_bounds__(256)
void gemm_mfma_kernel(const u16* __restrict__ A, const u16* __restrict__ BT,
                      const float* __restrict__ bias, void* __restrict__ Cout,
                      u16* __restrict__ VTout, int M, int N, int K)
{
    __shared__ u16 As[128 * 64];
    __shared__ u16 Bs[128 * 64];
    const int tid  = threadIdx.x;
    const int w    = tid >> 6;
    const int lane = tid & 63;
    const int li   = lane & 15;
    const int g    = lane >> 4;
    const int wm   = w >> 1, wn = w & 1;
    const int bm   = blockIdx.y * 128;
    const int bn   = blockIdx.x * 128;

    f32x4 acc[4][4];
    #pragma unroll
    for (int i = 0; i < 4; ++i)
        #pragma unroll
        for (int j = 0; j < 4; ++j)
            acc[i][j] = (f32x4){0.f, 0.f, 0.f, 0.f};

    for (int k0 = 0; k0 < K; k0 += 64) {
        __syncthreads();
        #pragma unroll
        for (int inst = 0; inst < 4; ++inst) {
            const int L   = inst * 256 + tid;
            const int row = L >> 3;
            const int gp  = (L & 7) ^ (row & 7);
            async_lds16(&As[(inst * 256 + w * 64) * 8],
                        &A[(size_t)(bm + row) * K + k0 + gp * 8]);
            async_lds16(&Bs[(inst * 256 + w * 64) * 8],
                        &BT[(size_t)(bn + row) * K + k0 + gp * 8]);
        }
        __syncthreads();

        #pragma unroll
        for (int kc = 0; kc < 2; ++kc) {
            bf16x8 af[4], bfr[4];
            #pragma unroll
            for (int fm = 0; fm < 4; ++fm) {
                const int off = (wm * 64 + fm * 16 + li) * 64 +
                                (((kc * 4 + g) * 8) ^ ((li & 7) * 8));
                af[fm] = *(const bf16x8*)&As[off];
            }
            #pragma unroll
            for (int fn = 0; fn < 4; ++fn) {
                const int off = (wn * 64 + fn * 16 + li) * 64 +
                                (((kc * 4 + g) * 8) ^ ((li & 7) * 8));
                bfr[fn] = *(const bf16x8*)&Bs[off];
            }
            #pragma unroll
            for (int fm = 0; fm < 4; ++fm)
                #pragma unroll
                for (int fn = 0; fn < 4; ++fn)
                    acc[fm][fn] = __builtin_amdgcn_mfma_f32_16x16x32_bf16(
                        af[fm], bfr[fn], acc[fm][fn], 0, 0, 0);
        }
    }

    if (MODE == 1 && bn >= 2 * Dn) {
        // V tile -> VT[b,h,d,t], 4 consecutive t rows packed per 8B store
        #pragma unroll
        for (int fm = 0; fm < 4; ++fm) {
            const int t0g = bm + wm * 64 + fm * 16 + g * 4;
            const int bb = t0g >> 10, tt = t0g & 1023;
            #pragma unroll
            for (int fn = 0; fn < 4; ++fn) {
                const int ncol = bn + wn * 64 + fn * 16 + li;
                const float bs = bias[ncol];
                const int cv = ncol - 2 * Dn;
                const int hv = cv >> 6, dv = cv & 63;
                union { u16 u[4]; uint2 p; } r;
                #pragma unroll
                for (int reg = 0; reg < 4; ++reg)
                    r.u[reg] = f2b(acc[fm][fn][reg] + bs);
                *(uint2*)&VTout[(((size_t)bb * Hn + hv) * HDn + dv) * Tn + tt] = r.p;
            }
        }
    } else {
        #pragma unroll
        for (int fm = 0; fm < 4; ++fm) {
            #pragma unroll
            for (int reg = 0; reg < 4; ++reg) {
                const size_t row = (size_t)(bm + wm * 64 + fm * 16 + g * 4 + reg);
                #pragma unroll
                for (int fn = 0; fn < 4; ++fn) {
                    const int col = bn + wn * 64 + fn * 16 + li;
                    const float v = acc[fm][fn][reg] + bias[col];
                    if (MODE == 1) ((u16*)Cout)[row * N + col] = f2b(v);
                    else           ((float*)Cout)[row * N + col] = v;
                }
            }
        }
    }
}

// ---------------------------------------------------------------------------
// Barrier-free MFMA flash attention (causal), SWAPPED QK^T.
// Block = 128 thr (2 waves); each wave owns 32 q-rows; block covers 64.
// S^T = mfma(K, Q): lane li holds all scores of q-row (rh*16+li) -> row
// reduce = in-lane + 2 shuffles. Defer-max (THR=8, exp2 domain) skips the
// O-rescale + cross-lane resc broadcast on most tiles. P goes through a
// per-wave LDS slice (packed 8B writes, same swizzle family / read path as
// the verified round-3 kernel). No __syncthreads anywhere.
// ---------------------------------------------------------------------------
__global__ __launch_bounds__(128)
void attn_mfma_kernel(const u16* __restrict__ qkvb, const u16* __restrict__ VT,
                      u16* __restrict__ attnb)
{
    __shared__ u16 Pb[2][32 * 64];   // per-wave P slice, col ^= (row&7)<<3

    const int tid  = threadIdx.x;
    const int w    = tid >> 6;
    const int lane = tid & 63;
    const int li   = lane & 15;
    const int g    = lane >> 4;

    // grid 1536: same-(b,h) pinned to one XCD (fid&7), longest qt first
    const int fid = blockIdx.x;
    const int xcd = fid & 7, j = fid >> 3;  // j 0..191
    const int bh  = xcd + 8 * (j % 12);     // 0..95
    const int qt  = 15 - (j / 12);          // 15..0
    const int b   = bh / 12, h = bh % 12;

    const int q0   = qt * 64;
    const int wrow = q0 + w * 32;           // wave's first q-row
    const size_t rowbase = (size_t)b * Tn;
    const u16* vbase = VT + (size_t)bh * HDn * Tn;

    // Q fragments (B operand), resident all kernel
    bf16x8 qf[2][2];
    #pragma unroll
    for (int rh = 0; rh < 2; ++rh)
        #pragma unroll
        for (int kc = 0; kc < 2; ++kc)
            qf[rh][kc] = *(const bf16x8*)&qkvb[
                (rowbase + wrow + rh * 16 + li) * D3 + h * HDn + kc * 32 + g * 8];

    f32x4 of[2][4];
    float m_run[2], l_run[2];
    #pragma unroll
    for (int rh = 0; rh < 2; ++rh) {
        #pragma unroll
        for (int nf = 0; nf < 4; ++nf) of[rh][nf] = (f32x4){0.f, 0.f, 0.f, 0.f};
        m_run[rh] = -1e30f;
        l_run[rh] = 0.f;
    }

    const int nkt = qt + 1;   // same for both waves in the block
    for (int kt = 0; kt < nkt; ++kt) {
        const int k0 = kt * 64;
        const bool maskit = (kt == nkt - 1);
        const u16* kbase = &qkvb[(rowbase + k0) * D3 + Dn + h * HDn];

        // S^T = K Q^T : lane holds keys {16nf+4g+reg} for q-row (rh*16+li)
        f32x4 st[2][4];
        #pragma unroll
        for (int rh = 0; rh < 2; ++rh)
            #pragma unroll
            for (int nf = 0; nf < 4; ++nf) st[rh][nf] = (f32x4){0.f, 0.f, 0.f, 0.f};
        #pragma unroll
        for (int kc = 0; kc < 2; ++kc) {
            #pragma unroll
            for (int nf = 0; nf < 4; ++nf) {
                const bf16x8 kf = *(const bf16x8*)&kbase[
                    (size_t)(nf * 16 + li) * D3 + kc * 32 + g * 8];
                st[0][nf] = __builtin_amdgcn_mfma_f32_16x16x32_bf16(kf, qf[0][kc], st[0][nf], 0, 0, 0);
                st[1][nf] = __builtin_amdgcn_mfma_f32_16x16x32_bf16(kf, qf[1][kc], st[1][nf], 0, 0, 0);
            }
        }

        #pragma unroll
        for (int rh = 0; rh < 2; ++rh) {
            const int qg = wrow + rh * 16 + li;
            float sv[4][4];
            float mt = -1e30f;
            #pragma unroll
            for (int nf = 0; nf < 4; ++nf)
                #pragma unroll
                for (int reg = 0; reg < 4; ++reg) {
                    float v = st[rh][nf][reg] * SM_SCALE;
                    if (maskit && (k0 + nf * 16 + g * 4 + reg > qg)) v = -1e30f;
                    sv[nf][reg] = v;
                    mt = fmaxf(mt, v);
                }
            mt = fmaxf(mt, __shfl_xor(mt, 16, 64));
            mt = fmaxf(mt, __shfl_xor(mt, 32, 64));

            const float mold = m_run[rh];
            if (!__all(mt <= mold + 8.0f)) {
                const float mnew = fmaxf(mold, mt);
                const float resc = exp2f(mold - mnew);
                m_run[rh] = mnew;
                l_run[rh] *= resc;
                float rs[4];
                #pragma unroll
                for (int reg = 0; reg < 4; ++reg)
                    rs[reg] = __shfl(resc, g * 4 + reg, 64);
                #pragma unroll
                for (int nf = 0; nf < 4; ++nf)
                    #pragma unroll
                    for (int reg = 0; reg < 4; ++reg)
                        of[rh][nf][reg] *= rs[reg];
            }

            const float mcur = m_run[rh];
            float ls = 0.f;
            u16* pb = &Pb[w][(rh * 16 + li) * 64];
            #pragma unroll
            for (int nf = 0; nf < 4; ++nf) {
                const float p0 = exp2f(sv[nf][0] - mcur);
                const float p1 = exp2f(sv[nf][1] - mcur);
                const float p2 = exp2f(sv[nf][2] - mcur);
                const float p3 = exp2f(sv[nf][3] - mcur);
                ls += (p0 + p1) + (p2 + p3);
                union { u16 u[4]; uint2 d; } pk;
                pk.u[0] = f2b(p0); pk.u[1] = f2b(p1);
                pk.u[2] = f2b(p2); pk.u[3] = f2b(p3);
                *(uint2*)&pb[(nf * 16 + g * 4) ^ ((li & 7) << 3)] = pk.d;
            }
            ls += __shfl_xor(ls, 16, 64);
            ls += __shfl_xor(ls, 32, 64);
            l_run[rh] += ls;
        }

        // O += P V : P from wave LDS slice (read path identical to round 3)
        #pragma unroll
        for (int kc = 0; kc < 2; ++kc) {
            const int pcol = (kc * 32 + g * 8) ^ ((li & 7) << 3);
            const bf16x8 pf0 = *(const bf16x8*)&Pb[w][li * 64 + pcol];
            const bf16x8 pf1 = *(const bf16x8*)&Pb[w][(16 + li) * 64 + pcol];
            #pragma unroll
            for (int nf = 0; nf < 4; ++nf) {
                const bf16x8 vf = *(const bf16x8*)&vbase[
                    (size_t)(nf * 16 + li) * Tn + k0 + kc * 32 + g * 8];
                of[0][nf] = __builtin_amdgcn_mfma_f32_16x16x32_bf16(pf0, vf, of[0][nf], 0, 0, 0);
                of[1][nf] = __builtin_amdgcn_mfma_f32_16x16x32_bf16(pf1, vf, of[1][nf], 0, 0, 0);
            }
        }
    }

    // epilogue: normalize (1/l broadcast to O-rows), store bf16 [B*T, D]
    #pragma unroll
    for (int rh = 0; rh < 2; ++rh) {
        const float inv = 1.0f / l_run[rh];
        float rs[4];
        #pragma unroll
        for (int reg = 0; reg < 4; ++reg)
            rs[reg] = __shfl(inv, g * 4 + reg, 64);
        #pragma unroll
        for (int reg = 0; reg < 4; ++reg) {
            const size_t row = rowbase + wrow + rh * 16 + g * 4 + reg;
            #pragma unroll
            for (int nf = 0; nf < 4; ++nf)
                attnb[row * Dn + h * HDn + nf * 16 + li] = f2b(of[rh][nf][reg] * rs[reg]);
        }
    }
}

extern "C" void kernel_launch(void* const* d_in, const int* in_sizes, int n_in,
                              void* d_out, int out_size, void* d_ws, size_t ws_size,
                              hipStream_t stream) {
    const float* x     = (const float*)d_in[0];
    const float* Wqkv  = (const float*)d_in[1];
    const float* bqkv  = (const float*)d_in[2];
    const float* Wproj = (const float*)d_in[3];
    const float* bproj = (const float*)d_in[4];
    float* out = (float*)d_out;

    const int M = Bn * Tn;   // 8192

    char* ws = (char*)d_ws;
    u16* qkvb   = (u16*)ws;  ws += (size_t)M * D3 * 2;        // 37.75 MB
    u16* xb     = (u16*)ws;  ws += (size_t)M * Dn * 2;        // 12.6 MB
    u16* attnb  = (u16*)ws;  ws += (size_t)M * Dn * 2;        // 12.6 MB
    u16* VT     = (u16*)ws;  ws += (size_t)Bn * Hn * HDn * Tn * 2; // 12.6 MB
    u16* WqkvT  = (u16*)ws;  ws += (size_t)D3 * Dn * 2;       // 3.5 MB
    u16* WprojT = (u16*)ws;                                   // 1.2 MB

    conv_bf16_kernel<<<(M * Dn / 4 + 255) / 256, 256, 0, stream>>>(x, xb, M * Dn);
    {
        dim3 gq(D3 / 64, Dn / 64);
        transpose_bf16_kernel<<<gq, 256, 0, stream>>>(Wqkv, WqkvT, Dn, D3);
        dim3 gp(Dn / 64, Dn / 64);
        transpose_bf16_kernel<<<gp, 256, 0, stream>>>(Wproj, WprojT, Dn, Dn);
    }
    {
        dim3 grid(D3 / 128, M / 128);
        gemm_mfma_kernel<1><<<grid, 256, 0, stream>>>(xb, WqkvT, bqkv, qkvb, VT, M, D3, Dn);
    }
    attn_mfma_kernel<<<1536, 128, 0, stream>>>(qkvb, VT, attnb);
    {
        dim3 grid(Dn / 128, M / 128);
        gemm_mfma_kernel<0><<<grid, 256, 0, stream>>>(attnb, WprojT, bproj, out, nullptr, M, Dn, Dn);
    }
}